// Round 6
// baseline (908.705 us; speedup 1.0000x reference)
//
#include <hip/hip_runtime.h>

constexpr int NN = 100000;
constexpr int NE = 640000;
constexpr int D  = 128;
constexpr int BINB = 128;                      // nodes per bin
constexpr int KB = (NN + BINB - 1) / BINB;     // 782 bins

typedef __attribute__((ext_vector_type(8))) short bf16x8;
typedef __attribute__((ext_vector_type(4))) float f32x4;

__device__ __forceinline__ short f2bf(float f) {
    union { float f; unsigned u; } v; v.f = f;
    unsigned r = v.u + 0x7FFF + ((v.u >> 16) & 1);
    return (short)(r >> 16);
}
__device__ __forceinline__ float bf2f(short h) {
    union { unsigned u; float f; } v;
    v.u = ((unsigned)(unsigned short)h) << 16;
    return v.f;
}

// ---------------------------------------------------------------------------
// Bin machinery: zero -> LDS histogram -> one-block scan (also inits cur)
// ---------------------------------------------------------------------------
__global__ __launch_bounds__(256) void k_bzero(int* __restrict__ cnt) {
    int i = blockIdx.x * 256 + threadIdx.x;
    if (i < KB) cnt[i] = 0;
}

__global__ __launch_bounds__(256) void k_bhist(const int* __restrict__ dst,
                                               int* __restrict__ cnt) {
    __shared__ int lh[KB];
    for (int i = threadIdx.x; i < KB; i += 256) lh[i] = 0;
    __syncthreads();
    for (int e = blockIdx.x * 256 + threadIdx.x; e < NE; e += gridDim.x * 256)
        atomicAdd(&lh[dst[e] >> 7], 1);
    __syncthreads();
    for (int i = threadIdx.x; i < KB; i += 256) {
        int v = lh[i];
        if (v) atomicAdd(&cnt[i], v);
    }
}

__global__ __launch_bounds__(1024) void k_bscan(const int* __restrict__ cnt,
                                                int* __restrict__ binoff,
                                                int* __restrict__ cur) {
    int t = threadIdx.x, lane = t & 63;
    int v = (t < KB) ? cnt[t] : 0;
    int incl = v;
#pragma unroll
    for (int s = 1; s < 64; s <<= 1) {
        int u = __shfl_up(incl, s, 64);
        if (lane >= s) incl += u;
    }
    __shared__ int wt[16], wp[16];
    if (lane == 63) wt[t >> 6] = incl;
    __syncthreads();
    if (t == 0) { int run = 0; for (int i = 0; i < 16; ++i) { wp[i] = run; run += wt[i]; } }
    __syncthreads();
    int excl = incl - v + wp[t >> 6];
    if (t < KB) { binoff[t] = excl; cur[t] = excl; }
    if (t == 0) binoff[KB] = NE;
}

// ---------------------------------------------------------------------------
// W pre-split: W[k][n] f32 -> Wt_hi[n][k], Wt_lo[n][k] bf16
// ---------------------------------------------------------------------------
__global__ __launch_bounds__(256) void k_wsplit(const float* __restrict__ W,
                                                short* __restrict__ Whi,
                                                short* __restrict__ Wlo) {
    for (int idx = blockIdx.x * 256 + threadIdx.x; idx < D * D; idx += gridDim.x * 256) {
        int n = idx >> 7, k = idx & 127;
        float w = W[k * D + n];
        short hi = f2bf(w);
        Whi[idx] = hi;
        Wlo[idx] = f2bf(w - bf2f(hi));
    }
}

// ---------------------------------------------------------------------------
// Pass A (edge order): append bf16(relu(x[src]+ea)) to the dst's bin.
// 16 threads/edge; group leader reserves the slot via atomicAdd(cur[bin]),
// __shfl broadcasts it. Writes cluster into 782 advancing fronts.
// ---------------------------------------------------------------------------
__global__ __launch_bounds__(256) void k_msg(const float* __restrict__ x,
                                             const int* __restrict__ src,
                                             const int* __restrict__ dst,
                                             const float* __restrict__ ea,
                                             int* __restrict__ cur,
                                             unsigned short* __restrict__ mdst,
                                             unsigned short* __restrict__ mbuf) {
    unsigned gid = blockIdx.x * 256 + threadIdx.x;
    unsigned e = gid >> 4;          // grid sized exactly: e < NE always
    unsigned c = gid & 15;
    const int lane = threadIdx.x & 63;
    const int s = src[e];
    const int d = dst[e];
    int slot = 0;
    if (c == 0) {
        slot = atomicAdd(&cur[d >> 7], 1);
        mdst[slot] = (unsigned short)(d & (BINB - 1));
    }
    slot = __shfl(slot, lane & 48, 64);   // broadcast from 16-group leader

    const float* xp  = x  + (size_t)s * D + c * 8;
    const float* eap = ea + (size_t)e * D + c * 8;
    float4 a0 = reinterpret_cast<const float4*>(xp)[0];
    float4 a1 = reinterpret_cast<const float4*>(xp)[1];
    float4 b0 = reinterpret_cast<const float4*>(eap)[0];
    float4 b1 = reinterpret_cast<const float4*>(eap)[1];
    float m[8] = {a0.x + b0.x, a0.y + b0.y, a0.z + b0.z, a0.w + b0.w,
                  a1.x + b1.x, a1.y + b1.y, a1.z + b1.z, a1.w + b1.w};
    bf16x8 o;
#pragma unroll
    for (int i = 0; i < 8; ++i) o[i] = f2bf(fmaxf(m[i], 0.0f));
    *reinterpret_cast<bf16x8*>(mbuf + (size_t)slot * D + c * 8) = o;
}

// ---------------------------------------------------------------------------
// Pass B (bin order): one block per bin. 64 KB LDS f32 accumulator for the
// bin's 128 nodes. Sequential read of the bin's message segment (8-deep
// batched loads), ds_add_f32 accumulate, then h = acc + (1+eps)x -> out.
// ---------------------------------------------------------------------------
__global__ __launch_bounds__(256) void k_bagg(const float* __restrict__ x,
                                              const unsigned short* __restrict__ mbuf,
                                              const unsigned short* __restrict__ mdst,
                                              const int* __restrict__ binoff,
                                              const float* __restrict__ eps,
                                              float* __restrict__ h) {
    __shared__ float acc[BINB * D];  // 64 KB
    float4* a4 = reinterpret_cast<float4*>(acc);
    for (int i = threadIdx.x; i < BINB * D / 4; i += 256) {
        float4 z; z.x = 0.f; z.y = 0.f; z.z = 0.f; z.w = 0.f;
        a4[i] = z;
    }
    __syncthreads();

    const int b = blockIdx.x;
    const int wave = threadIdx.x >> 6;
    const int lane = threadIdx.x & 63;
    const int j0 = binoff[b], j1 = binoff[b + 1];
    const int lo2 = lane * 2;

    const int base = j0 + wave;
    const int nmine = (j1 - base + 3) >> 2;  // my msgs: base + 4*i < j1
    for (int i0 = 0; i0 < nmine; i0 += 8) {
        ushort2 mv[8];
        int ld[8];
        bool ok[8];
#pragma unroll
        for (int q = 0; q < 8; ++q) {
            int j = base + 4 * (i0 + q);
            ok[q] = j < j1;
            int jc = ok[q] ? j : (j1 - 1);
            mv[q] = *reinterpret_cast<const ushort2*>(mbuf + (size_t)jc * D + lo2);
            ld[q] = mdst[jc];
        }
#pragma unroll
        for (int q = 0; q < 8; ++q) {
            if (ok[q]) {
                atomicAdd(&acc[ld[q] * D + lo2],     bf2f((short)mv[q].x));
                atomicAdd(&acc[ld[q] * D + lo2 + 1], bf2f((short)mv[q].y));
            }
        }
    }
    __syncthreads();

    const float sc = 1.0f + eps[0];
    const long n0 = (long)b * BINB;
    for (int v = threadIdx.x; v < BINB * (D / 4); v += 256) {
        int row = v >> 5, q = v & 31;
        long node = n0 + row;
        if (node < NN) {
            float4 a = a4[v];
            float4 xx = reinterpret_cast<const float4*>(x)[node * (D / 4) + q];
            float4 o;
            o.x = fmaf(sc, xx.x, a.x);
            o.y = fmaf(sc, xx.y, a.y);
            o.z = fmaf(sc, xx.z, a.z);
            o.w = fmaf(sc, xx.w, a.w);
            reinterpret_cast<float4*>(h)[node * (D / 4) + q] = o;
        }
    }
}

// ---------------------------------------------------------------------------
// Fused 2-layer MLP via bf16x3 MFMA (unchanged from round 4/5).
// ---------------------------------------------------------------------------
__global__ __launch_bounds__(256) void k_mlp2(const float* __restrict__ A,
                                              const short* __restrict__ W1h,
                                              const short* __restrict__ W1l,
                                              const short* __restrict__ W2h,
                                              const short* __restrict__ W2l,
                                              const float* __restrict__ b1,
                                              const float* __restrict__ b2,
                                              float* __restrict__ out) {
    __shared__ float G[4][32][D];  // 64 KB, per-wave 16 KB tiles

    const int wave = threadIdx.x >> 6;
    const int lane = threadIdx.x & 63;
    const int r = lane & 15;
    const int g = lane >> 4;

    const long rb = (long)blockIdx.x * 128 + wave * 32;

    f32x4 acc1[2][8];
#pragma unroll
    for (int mt = 0; mt < 2; ++mt)
#pragma unroll
        for (int nt = 0; nt < 8; ++nt) {
            acc1[mt][nt].x = 0.f; acc1[mt][nt].y = 0.f;
            acc1[mt][nt].z = 0.f; acc1[mt][nt].w = 0.f;
        }

#pragma unroll
    for (int kc = 0; kc < 4; ++kc) {
        const int k0 = kc * 32;
        bf16x8 ahi[2], alo[2];
#pragma unroll
        for (int mt = 0; mt < 2; ++mt) {
            long row = rb + mt * 16 + r;
            row = (row < NN) ? row : (NN - 1);
            const float* ap = A + row * D + k0 + g * 8;
            float4 v0 = reinterpret_cast<const float4*>(ap)[0];
            float4 v1 = reinterpret_cast<const float4*>(ap)[1];
            float vals[8] = {v0.x, v0.y, v0.z, v0.w, v1.x, v1.y, v1.z, v1.w};
#pragma unroll
            for (int i = 0; i < 8; ++i) {
                short hb = f2bf(vals[i]);
                ahi[mt][i] = hb;
                alo[mt][i] = f2bf(vals[i] - bf2f(hb));
            }
        }
#pragma unroll
        for (int nt = 0; nt < 8; ++nt) {
            const int wb = (nt * 16 + r) * D + k0 + g * 8;
            bf16x8 whi = *reinterpret_cast<const bf16x8*>(&W1h[wb]);
            bf16x8 wlo = *reinterpret_cast<const bf16x8*>(&W1l[wb]);
#pragma unroll
            for (int mt = 0; mt < 2; ++mt) {
                acc1[mt][nt] = __builtin_amdgcn_mfma_f32_16x16x32_bf16(ahi[mt], whi, acc1[mt][nt], 0, 0, 0);
                acc1[mt][nt] = __builtin_amdgcn_mfma_f32_16x16x32_bf16(ahi[mt], wlo, acc1[mt][nt], 0, 0, 0);
                acc1[mt][nt] = __builtin_amdgcn_mfma_f32_16x16x32_bf16(alo[mt], whi, acc1[mt][nt], 0, 0, 0);
            }
        }
    }

#pragma unroll
    for (int nt = 0; nt < 8; ++nt) {
        const int col = nt * 16 + r;
        const float bb = b1[col];
#pragma unroll
        for (int mt = 0; mt < 2; ++mt) {
#pragma unroll
            for (int q = 0; q < 4; ++q) {
                float v = fmaxf(acc1[mt][nt][q] + bb, 0.0f);
                G[wave][mt * 16 + g * 4 + q][col] = v;
            }
        }
    }
    __syncthreads();

    f32x4 acc2[2][8];
#pragma unroll
    for (int mt = 0; mt < 2; ++mt)
#pragma unroll
        for (int nt = 0; nt < 8; ++nt) {
            acc2[mt][nt].x = 0.f; acc2[mt][nt].y = 0.f;
            acc2[mt][nt].z = 0.f; acc2[mt][nt].w = 0.f;
        }

#pragma unroll
    for (int kc = 0; kc < 4; ++kc) {
        const int k0 = kc * 32;
        bf16x8 ahi[2], alo[2];
#pragma unroll
        for (int mt = 0; mt < 2; ++mt) {
            const float* gp = &G[wave][mt * 16 + r][k0 + g * 8];
            float4 v0 = reinterpret_cast<const float4*>(gp)[0];
            float4 v1 = reinterpret_cast<const float4*>(gp)[1];
            float vals[8] = {v0.x, v0.y, v0.z, v0.w, v1.x, v1.y, v1.z, v1.w};
#pragma unroll
            for (int i = 0; i < 8; ++i) {
                short hb = f2bf(vals[i]);
                ahi[mt][i] = hb;
                alo[mt][i] = f2bf(vals[i] - bf2f(hb));
            }
        }
#pragma unroll
        for (int nt = 0; nt < 8; ++nt) {
            const int wb = (nt * 16 + r) * D + k0 + g * 8;
            bf16x8 whi = *reinterpret_cast<const bf16x8*>(&W2h[wb]);
            bf16x8 wlo = *reinterpret_cast<const bf16x8*>(&W2l[wb]);
#pragma unroll
            for (int mt = 0; mt < 2; ++mt) {
                acc2[mt][nt] = __builtin_amdgcn_mfma_f32_16x16x32_bf16(ahi[mt], whi, acc2[mt][nt], 0, 0, 0);
                acc2[mt][nt] = __builtin_amdgcn_mfma_f32_16x16x32_bf16(ahi[mt], wlo, acc2[mt][nt], 0, 0, 0);
                acc2[mt][nt] = __builtin_amdgcn_mfma_f32_16x16x32_bf16(alo[mt], whi, acc2[mt][nt], 0, 0, 0);
            }
        }
    }

#pragma unroll
    for (int nt = 0; nt < 8; ++nt) {
        const int col = nt * 16 + r;
        const float bb = b2[col];
#pragma unroll
        for (int mt = 0; mt < 2; ++mt) {
#pragma unroll
            for (int q = 0; q < 4; ++q) {
                long row = rb + mt * 16 + g * 4 + q;
                if (row < NN) out[row * D + col] = acc2[mt][nt][q] + bb;
            }
        }
    }
}

// ---------------------------------------------------------------------------
extern "C" void kernel_launch(void* const* d_in, const int* in_sizes, int n_in,
                              void* d_out, int out_size, void* d_ws, size_t ws_size,
                              hipStream_t stream) {
    const float* x   = (const float*)d_in[0];
    const int*   ei  = (const int*)d_in[1];   // int32 [2, NE]
    const float* ea  = (const float*)d_in[2];
    const float* eps = (const float*)d_in[3];
    const float* W1  = (const float*)d_in[4];
    const float* b1  = (const float*)d_in[5];
    const float* W2  = (const float*)d_in[6];
    const float* b2  = (const float*)d_in[7];
    float* out = (float*)d_out;

    const int* src = ei;
    const int* dst = ei + NE;

    // ws layout
    int* cnt    = (int*)d_ws;                            // KB
    int* binoff = cnt + KB;                              // KB+1
    int* cur    = binoff + KB + 1;                       // KB
    unsigned short* mdst = (unsigned short*)(cur + KB);  // NE
    size_t mb_off = (((size_t)(3 * KB + 1) * 4 + (size_t)NE * 2) + 255) & ~(size_t)255;
    unsigned short* mbuf = (unsigned short*)((char*)d_ws + mb_off);  // NE*D bf16
    short* wsp = (short*)(mbuf + (size_t)NE * D);
    short* W1h = wsp;
    short* W1l = W1h + D * D;
    short* W2h = W1l + D * D;
    short* W2l = W2h + D * D;

    k_wsplit<<<32, 256, 0, stream>>>(W1, W1h, W1l);
    k_wsplit<<<32, 256, 0, stream>>>(W2, W2h, W2l);
    k_bzero <<<(KB + 255) / 256, 256, 0, stream>>>(cnt);
    k_bhist <<<256, 256, 0, stream>>>(dst, cnt);
    k_bscan <<<1, 1024, 0, stream>>>(cnt, binoff, cur);

    // Pass A: edge-order streaming, binned append
    k_msg<<<NE * 16 / 256, 256, 0, stream>>>(x, src, dst, ea, cur, mdst, mbuf);
    // Pass B: bin-order streaming, LDS accumulate -> h in d_out
    k_bagg<<<KB, 256, 0, stream>>>(x, mbuf, mdst, binoff, eps, out);
    // out = relu(out @ W1 + b1) @ W2 + b2
    k_mlp2<<<(NN + 127) / 128, 256, 0, stream>>>(out, W1h, W1l, W2h, W2l, b1, b2, out);
}

// Round 7
// 265.302 us; speedup vs baseline: 3.4252x; 3.4252x over previous
//
#include <hip/hip_runtime.h>
#include <hip/hip_bf16.h>

constexpr int NN = 100000;
constexpr int NE = 640000;
constexpr int D  = 128;
constexpr int NB = (NN + 255) / 256;  // 391

typedef __attribute__((ext_vector_type(8))) short bf16x8;
typedef __attribute__((ext_vector_type(4))) float f32x4;

__device__ __forceinline__ short f2bf(float f) {
    union { float f; unsigned u; } v; v.f = f;
    unsigned r = v.u + 0x7FFF + ((v.u >> 16) & 1);
    return (short)(r >> 16);
}
__device__ __forceinline__ float bf2f(short h) {
    union { unsigned u; float f; } v;
    v.u = ((unsigned)(unsigned short)h) << 16;
    return v.f;
}
// packed RTNE f32x2 -> bf16x2 via v_cvt_pk_bf16_f32 (compiler-emitted)
__device__ __forceinline__ unsigned cvtpk(float a, float b) {
    union { __hip_bfloat162 h2; unsigned u; } cv;
    float2 f; f.x = a; f.y = b;
    cv.h2 = __float22bfloat162_rn(f);
    return cv.u;
}
__device__ __forceinline__ void pack_hilo(const float* v, bf16x8& hi, bf16x8& lo) {
#pragma unroll
    for (int i = 0; i < 4; ++i) {
        unsigned u = cvtpk(v[2 * i], v[2 * i + 1]);
        short h0 = (short)(u & 0xFFFF), h1 = (short)(u >> 16);
        hi[2 * i] = h0; hi[2 * i + 1] = h1;
        unsigned ul = cvtpk(v[2 * i] - bf2f(h0), v[2 * i + 1] - bf2f(h1));
        lo[2 * i] = (short)(ul & 0xFFFF); lo[2 * i + 1] = (short)(ul >> 16);
    }
}
__device__ __forceinline__ bf16x8 pack_bf8(const float* v) {
    bf16x8 o;
#pragma unroll
    for (int i = 0; i < 4; ++i) {
        unsigned u = cvtpk(v[2 * i], v[2 * i + 1]);
        o[2 * i] = (short)(u & 0xFFFF); o[2 * i + 1] = (short)(u >> 16);
    }
    return o;
}

// ---------------------------------------------------------------------------
// Counting sort of edges by dst (round-2/4 proven chain)
// ---------------------------------------------------------------------------
__global__ __launch_bounds__(256) void k_zero(int* __restrict__ cnt) {
    int i = blockIdx.x * 256 + threadIdx.x;
    if (i < NN) cnt[i] = 0;
}

__global__ __launch_bounds__(256) void k_hist(const int* __restrict__ dst,
                                              int* __restrict__ cnt) {
    int e = blockIdx.x * 256 + threadIdx.x;
    if (e < NE) atomicAdd(&cnt[dst[e]], 1);
}

__global__ __launch_bounds__(256) void k_bsum(const int* __restrict__ cnt,
                                              int* __restrict__ bsum) {
    int i = blockIdx.x * 256 + threadIdx.x;
    int v = (i < NN) ? cnt[i] : 0;
#pragma unroll
    for (int s = 32; s; s >>= 1) v += __shfl_down(v, s, 64);
    __shared__ int w[4];
    if ((threadIdx.x & 63) == 0) w[threadIdx.x >> 6] = v;
    __syncthreads();
    if (threadIdx.x == 0) bsum[blockIdx.x] = w[0] + w[1] + w[2] + w[3];
}

__global__ __launch_bounds__(512) void k_scan_bsum(const int* __restrict__ bsum,
                                                   int* __restrict__ bboff) {
    int t = threadIdx.x, lane = t & 63;
    int v = (t < NB) ? bsum[t] : 0;
    int incl = v;
#pragma unroll
    for (int s = 1; s < 64; s <<= 1) {
        int u = __shfl_up(incl, s, 64);
        if (lane >= s) incl += u;
    }
    __shared__ int wt[8], wp[8];
    if (lane == 63) wt[t >> 6] = incl;
    __syncthreads();
    if (t == 0) { int run = 0; for (int i = 0; i < 8; ++i) { wp[i] = run; run += wt[i]; } }
    __syncthreads();
    if (t < NB) bboff[t] = incl - v + wp[t >> 6];
}

__global__ __launch_bounds__(256) void k_scan_final(const int* __restrict__ cnt,
                                                    const int* __restrict__ bboff,
                                                    int* __restrict__ off,
                                                    int* __restrict__ cur) {
    int b = blockIdx.x, t = threadIdx.x, lane = t & 63;
    int i = b * 256 + t;
    int v = (i < NN) ? cnt[i] : 0;
    int incl = v;
#pragma unroll
    for (int s = 1; s < 64; s <<= 1) {
        int u = __shfl_up(incl, s, 64);
        if (lane >= s) incl += u;
    }
    __shared__ int wt[4], wp[4];
    if (lane == 63) wt[t >> 6] = incl;
    __syncthreads();
    if (t == 0) { int run = 0; for (int q = 0; q < 4; ++q) { wp[q] = run; run += wt[q]; } }
    __syncthreads();
    int excl = incl - v + wp[t >> 6] + bboff[b];
    if (i < NN) { off[i] = excl; cur[i] = excl; }
    if (i == 0) off[NN] = NE;
}

__global__ __launch_bounds__(256) void k_perm(const int* __restrict__ dst,
                                              const int* __restrict__ src,
                                              int* __restrict__ cur,
                                              int2* __restrict__ ps) {
    int e = blockIdx.x * 256 + threadIdx.x;
    if (e < NE) {
        int p = atomicAdd(&cur[dst[e]], 1);
        int2 v; v.x = e; v.y = src[e];
        ps[p] = v;
    }
}

// ---------------------------------------------------------------------------
// W pre-split: W[k][n] f32 -> Wt_hi[n][k], Wt_lo[n][k] bf16
// ---------------------------------------------------------------------------
__global__ __launch_bounds__(256) void k_wsplit(const float* __restrict__ W,
                                                short* __restrict__ Whi,
                                                short* __restrict__ Wlo) {
    for (int idx = blockIdx.x * 256 + threadIdx.x; idx < D * D; idx += gridDim.x * 256) {
        int n = idx >> 7, k = idx & 127;
        float w = W[k * D + n];
        short hi = f2bf(w);
        Whi[idx] = hi;
        Wlo[idx] = f2bf(w - bf2f(hi));
    }
}

// ---------------------------------------------------------------------------
// Fused aggregation + 2-layer MLP. Block = 256 thr (4 waves) owns 32
// consecutive dst nodes (NN = 3125 * 32 exactly -> no bounds checks).
//   phase 1: wave w gathers+aggregates nodes [nb+8w, nb+8w+8) -> LDS G1
//   phase 2a: layer 1 (A=G1 hi/lo x W1 hi/lo, 3-term MFMA) -> relu -> G2
//   phase 2b: layer 2 (A=G2 single-bf16 x W2 hi/lo, 2-term) -> out
// LDS rows padded to 132 floats: ds_read_b128 conflicts 16-way -> 2-way.
// ---------------------------------------------------------------------------
constexpr int LDG = 132;  // padded row stride (floats)

__global__ __launch_bounds__(256) void k_fused(const float* __restrict__ x,
                                               const float* __restrict__ ea,
                                               const int* __restrict__ off,
                                               const int2* __restrict__ ps,
                                               const float* __restrict__ eps,
                                               const short* __restrict__ W1h,
                                               const short* __restrict__ W1l,
                                               const short* __restrict__ W2h,
                                               const short* __restrict__ W2l,
                                               const float* __restrict__ b1,
                                               const float* __restrict__ b2,
                                               float* __restrict__ out) {
    __shared__ float G1[32 * LDG];  // 16.9 KB
    __shared__ float G2[32 * LDG];  // 16.9 KB

    const int wave = threadIdx.x >> 6;
    const int lane = threadIdx.x & 63;
    const int nb = blockIdx.x * 32;

    // ---------------- phase 1: gather-aggregate 8 nodes per wave ----------
    {
        const int lo2 = lane * 2;
        const float sc = 1.0f + eps[0];
        for (int t = 0; t < 8; ++t) {
            const int n = nb + wave * 8 + t;
            const int j0 = off[n], j1 = off[n + 1];
            float accx = 0.0f, accy = 0.0f;
            for (int j = j0; j < j1; j += 8) {
                int ee[8], ss[8];
#pragma unroll
                for (int q = 0; q < 8; ++q) {
                    int jj = j + q; jj = (jj < j1) ? jj : (j1 - 1);
                    int2 p = ps[jj];
                    ee[q] = p.x; ss[q] = p.y;
                }
                float2 xa[8], eb[8];
#pragma unroll
                for (int q = 0; q < 8; ++q) {
                    xa[q] = *reinterpret_cast<const float2*>(x  + (size_t)ss[q] * D + lo2);
                    eb[q] = *reinterpret_cast<const float2*>(ea + (size_t)ee[q] * D + lo2);
                }
#pragma unroll
                for (int q = 0; q < 8; ++q) {
                    float mx = fmaxf(xa[q].x + eb[q].x, 0.0f);
                    float my = fmaxf(xa[q].y + eb[q].y, 0.0f);
                    bool ok = (j + q) < j1;
                    accx += ok ? mx : 0.0f;
                    accy += ok ? my : 0.0f;
                }
            }
            float2 xx = *reinterpret_cast<const float2*>(x + (size_t)n * D + lo2);
            float2 o;
            o.x = fmaf(sc, xx.x, accx);
            o.y = fmaf(sc, xx.y, accy);
            *reinterpret_cast<float2*>(&G1[(wave * 8 + t) * LDG + lo2]) = o;
        }
    }
    __syncthreads();

    const int r = lane & 15;   // row within 16-tile / W col within 16-tile
    const int g = lane >> 4;   // k-group (8) / D-row group (4)

    // ---------------- phase 2a: layer 1 (3-term bf16 MFMA) ----------------
    {
        f32x4 acc[2][2];
#pragma unroll
        for (int mt = 0; mt < 2; ++mt)
#pragma unroll
            for (int nl = 0; nl < 2; ++nl) {
                acc[mt][nl].x = 0.f; acc[mt][nl].y = 0.f;
                acc[mt][nl].z = 0.f; acc[mt][nl].w = 0.f;
            }

#pragma unroll
        for (int kc = 0; kc < 4; ++kc) {
            const int k0 = kc * 32;
            bf16x8 ahi[2], alo[2];
#pragma unroll
            for (int mt = 0; mt < 2; ++mt) {
                const float* gp = &G1[(mt * 16 + r) * LDG + k0 + g * 8];
                float vals[8];
                *reinterpret_cast<float4*>(&vals[0]) = reinterpret_cast<const float4*>(gp)[0];
                *reinterpret_cast<float4*>(&vals[4]) = reinterpret_cast<const float4*>(gp)[1];
                pack_hilo(vals, ahi[mt], alo[mt]);
            }
#pragma unroll
            for (int nl = 0; nl < 2; ++nl) {
                const int nt = wave * 2 + nl;
                const int wb = (nt * 16 + r) * D + k0 + g * 8;
                bf16x8 whi = *reinterpret_cast<const bf16x8*>(&W1h[wb]);
                bf16x8 wlo = *reinterpret_cast<const bf16x8*>(&W1l[wb]);
#pragma unroll
                for (int mt = 0; mt < 2; ++mt) {
                    acc[mt][nl] = __builtin_amdgcn_mfma_f32_16x16x32_bf16(ahi[mt], whi, acc[mt][nl], 0, 0, 0);
                    acc[mt][nl] = __builtin_amdgcn_mfma_f32_16x16x32_bf16(ahi[mt], wlo, acc[mt][nl], 0, 0, 0);
                    acc[mt][nl] = __builtin_amdgcn_mfma_f32_16x16x32_bf16(alo[mt], whi, acc[mt][nl], 0, 0, 0);
                }
            }
        }

        // epilogue: bias + relu -> G2 (row = mt*16 + g*4 + q, col = nt*16 + r)
#pragma unroll
        for (int nl = 0; nl < 2; ++nl) {
            const int col = (wave * 2 + nl) * 16 + r;
            const float bb = b1[col];
#pragma unroll
            for (int mt = 0; mt < 2; ++mt)
#pragma unroll
                for (int q = 0; q < 4; ++q)
                    G2[(mt * 16 + g * 4 + q) * LDG + col] = fmaxf(acc[mt][nl][q] + bb, 0.0f);
        }
    }
    __syncthreads();

    // ---------------- phase 2b: layer 2 (2-term, single-bf16 A) -----------
    {
        f32x4 acc[2][2];
#pragma unroll
        for (int mt = 0; mt < 2; ++mt)
#pragma unroll
            for (int nl = 0; nl < 2; ++nl) {
                acc[mt][nl].x = 0.f; acc[mt][nl].y = 0.f;
                acc[mt][nl].z = 0.f; acc[mt][nl].w = 0.f;
            }

#pragma unroll
        for (int kc = 0; kc < 4; ++kc) {
            const int k0 = kc * 32;
            bf16x8 a[2];
#pragma unroll
            for (int mt = 0; mt < 2; ++mt) {
                const float* gp = &G2[(mt * 16 + r) * LDG + k0 + g * 8];
                float vals[8];
                *reinterpret_cast<float4*>(&vals[0]) = reinterpret_cast<const float4*>(gp)[0];
                *reinterpret_cast<float4*>(&vals[4]) = reinterpret_cast<const float4*>(gp)[1];
                a[mt] = pack_bf8(vals);
            }
#pragma unroll
            for (int nl = 0; nl < 2; ++nl) {
                const int nt = wave * 2 + nl;
                const int wb = (nt * 16 + r) * D + k0 + g * 8;
                bf16x8 whi = *reinterpret_cast<const bf16x8*>(&W2h[wb]);
                bf16x8 wlo = *reinterpret_cast<const bf16x8*>(&W2l[wb]);
#pragma unroll
                for (int mt = 0; mt < 2; ++mt) {
                    acc[mt][nl] = __builtin_amdgcn_mfma_f32_16x16x32_bf16(a[mt], whi, acc[mt][nl], 0, 0, 0);
                    acc[mt][nl] = __builtin_amdgcn_mfma_f32_16x16x32_bf16(a[mt], wlo, acc[mt][nl], 0, 0, 0);
                }
            }
        }

#pragma unroll
        for (int nl = 0; nl < 2; ++nl) {
            const int col = (wave * 2 + nl) * 16 + r;
            const float bb = b2[col];
#pragma unroll
            for (int mt = 0; mt < 2; ++mt)
#pragma unroll
                for (int q = 0; q < 4; ++q) {
                    long row = nb + mt * 16 + g * 4 + q;
                    out[row * D + col] = acc[mt][nl][q] + bb;
                }
        }
    }
}

// ---------------------------------------------------------------------------
extern "C" void kernel_launch(void* const* d_in, const int* in_sizes, int n_in,
                              void* d_out, int out_size, void* d_ws, size_t ws_size,
                              hipStream_t stream) {
    const float* x   = (const float*)d_in[0];
    const int*   ei  = (const int*)d_in[1];   // int32 [2, NE]
    const float* ea  = (const float*)d_in[2];
    const float* eps = (const float*)d_in[3];
    const float* W1  = (const float*)d_in[4];
    const float* b1  = (const float*)d_in[5];
    const float* W2  = (const float*)d_in[6];
    const float* b2  = (const float*)d_in[7];
    float* out = (float*)d_out;

    const int* src = ei;
    const int* dst = ei + NE;

    // ws layout (~6.5 MB)
    int* base  = (int*)d_ws;
    int* cnt   = base;                 // NN
    int* off   = cnt + NN;             // NN+1
    int* cur   = off + NN + 1;         // NN
    int* bsum  = cur + NN;             // NB
    int* bboff = bsum + NB;            // NB
    size_t ps_off = ((size_t)(3 * NN + 1 + 2 * NB) + 1) & ~(size_t)1;
    int2* ps   = (int2*)(base + ps_off);               // NE int2
    short* wsp = (short*)(base + ps_off + 2 * (size_t)NE);
    short* W1h = wsp;                  // D*D each
    short* W1l = W1h + D * D;
    short* W2h = W1l + D * D;
    short* W2l = W2h + D * D;

    k_wsplit    <<<32,               256, 0, stream>>>(W1, W1h, W1l);
    k_wsplit    <<<32,               256, 0, stream>>>(W2, W2h, W2l);
    k_zero      <<<NB,               256, 0, stream>>>(cnt);
    k_hist      <<<(NE + 255) / 256, 256, 0, stream>>>(dst, cnt);
    k_bsum      <<<NB,               256, 0, stream>>>(cnt, bsum);
    k_scan_bsum <<<1,                512, 0, stream>>>(bsum, bboff);
    k_scan_final<<<NB,               256, 0, stream>>>(cnt, bboff, off, cur);
    k_perm      <<<(NE + 255) / 256, 256, 0, stream>>>(dst, src, cur, ps);

    // fused: gather-aggregate -> LDS -> 2-layer MFMA MLP -> out
    k_fused<<<NN / 32, 256, 0, stream>>>(x, ea, off, ps, eps,
                                         W1h, W1l, W2h, W2l, b1, b2, out);
}